// Round 2
// baseline (60.266 us; speedup 1.0000x reference)
//
#include <hip/hip_runtime.h>

#define N_INPUTS   1024
#define MAX_HIDDEN 2048
#define MAX_LAYERS 4
#define TOTAL_HIDDEN (MAX_HIDDEN * MAX_LAYERS)      // 8192
#define N_OUTPUTS  512
#define MAX_CONN   2048
#define MAX_OUT_CONN 4096
#define N_VALUES   (N_INPUTS + TOTAL_HIDDEN)        // 9216

__global__ void init_values_kernel(const float* __restrict__ in, float* __restrict__ vals) {
    int i = blockIdx.x * blockDim.x + threadIdx.x;
    if (i < N_INPUTS) vals[i] = in[i];
}

// One neuron per wave. Block stages values[0:stage_bound) into LDS (zeros beyond),
// then each wave reduces CONNS connections for its neuron.
// Masks are int32 (numpy bool widened by the harness).
template<int CONNS, bool TANH>
__global__ void neuron_kernel(const float* __restrict__ g_values,
                              const int* __restrict__ ids,       // rows of CONNS, offset by row_base
                              const float* __restrict__ wts,
                              const int* __restrict__ cmask,     // int32 0/1 per connection
                              const int* __restrict__ amask,     // int32 0/1 per neuron (already offset)
                              float* __restrict__ out,           // per-neuron output (already offset)
                              int row_base,
                              int stage_bound)
{
    __shared__ float vals[N_VALUES];

    // ---- stage values -> LDS (vectorized), zero beyond stage_bound ----
    {
        const float4* g4 = reinterpret_cast<const float4*>(g_values);
        float4* s4 = reinterpret_cast<float4*>(vals);
        const int bound4 = stage_bound >> 2;
        for (int i = threadIdx.x; i < (N_VALUES >> 2); i += blockDim.x) {
            float4 v;
            if (i < bound4) v = g4[i];
            else { v.x = 0.f; v.y = 0.f; v.z = 0.f; v.w = 0.f; }
            s4[i] = v;
        }
    }
    __syncthreads();

    const int wave = threadIdx.x >> 6;
    const int lane = threadIdx.x & 63;
    const int nwaves = blockDim.x >> 6;

    const int neuron = blockIdx.x * nwaves + wave;   // one neuron per wave

    const size_t row = (size_t)(row_base + neuron) * CONNS;
    const int* __restrict__ idrow = ids + row;
    const float* __restrict__ wrow = wts + row;
    const int* __restrict__ mrow = cmask + row;

    float sum = 0.f;
    #pragma unroll
    for (int c = lane * 8; c < CONNS; c += 64 * 8) {
        const int4* ip = reinterpret_cast<const int4*>(idrow + c);
        const float4* wp = reinterpret_cast<const float4*>(wrow + c);
        const int4* mp = reinterpret_cast<const int4*>(mrow + c);
        int4 ia = ip[0], ib = ip[1];
        float4 wa = wp[0], wb = wp[1];
        int4 ma = mp[0], mb = mp[1];

        float v0 = vals[ia.x], v1 = vals[ia.y], v2 = vals[ia.z], v3 = vals[ia.w];
        float v4 = vals[ib.x], v5 = vals[ib.y], v6 = vals[ib.z], v7 = vals[ib.w];

        if (ma.x == 0) v0 = 0.f;
        if (ma.y == 0) v1 = 0.f;
        if (ma.z == 0) v2 = 0.f;
        if (ma.w == 0) v3 = 0.f;
        if (mb.x == 0) v4 = 0.f;
        if (mb.y == 0) v5 = 0.f;
        if (mb.z == 0) v6 = 0.f;
        if (mb.w == 0) v7 = 0.f;

        sum = fmaf(v0, wa.x, sum);
        sum = fmaf(v1, wa.y, sum);
        sum = fmaf(v2, wa.z, sum);
        sum = fmaf(v3, wa.w, sum);
        sum = fmaf(v4, wb.x, sum);
        sum = fmaf(v5, wb.y, sum);
        sum = fmaf(v6, wb.z, sum);
        sum = fmaf(v7, wb.w, sum);
    }

    // ---- wave reduction (64 lanes) ----
    #pragma unroll
    for (int off = 32; off > 0; off >>= 1)
        sum += __shfl_xor(sum, off, 64);

    if (lane == 0) {
        if (TANH) {
            float a = tanhf(sum);
            if (amask[neuron] == 0) a = 0.f;
            out[neuron] = a;
        } else {
            out[neuron] = sum;
        }
    }
}

extern "C" void kernel_launch(void* const* d_in, const int* in_sizes, int n_in,
                              void* d_out, int out_size, void* d_ws, size_t ws_size,
                              hipStream_t stream) {
    const float* input_values = (const float*)d_in[0];
    const int*   h_ids        = (const int*)d_in[1];
    const float* h_w          = (const float*)d_in[2];
    const int*   h_cm         = (const int*)d_in[3];
    const int*   h_am         = (const int*)d_in[4];
    const int*   o_ids        = (const int*)d_in[5];
    const float* o_w          = (const float*)d_in[6];
    const int*   o_cm         = (const int*)d_in[7];
    float* out  = (float*)d_out;
    float* vals = (float*)d_ws;   // running values array: 9216 floats

    init_values_kernel<<<4, 256, 0, stream>>>(input_values, vals);

    // Hidden layers: 2048 neurons each, 8 waves/block (512 thr), 1 neuron/wave -> 256 blocks
    for (int k = 0; k < MAX_LAYERS; ++k) {
        const int start = k * MAX_HIDDEN;
        neuron_kernel<MAX_CONN, true><<<MAX_HIDDEN / 8, 512, 0, stream>>>(
            vals, h_ids, h_w, h_cm,
            h_am + start,
            vals + N_INPUTS + start,
            start,
            N_INPUTS + start);
    }

    // Output layer: 512 neurons, 4 waves/block (256 thr), 1 neuron/wave -> 128 blocks
    neuron_kernel<MAX_OUT_CONN, false><<<N_OUTPUTS / 4, 256, 0, stream>>>(
        vals, o_ids, o_w, o_cm,
        nullptr,
        out,
        0,
        N_VALUES);
}